// Round 1
// baseline (1806.428 us; speedup 1.0000x reference)
//
#include <hip/hip_runtime.h>
#include <math.h>

#define EE 4
#define BB 16384
#define NN 1024
#define FF 64
#define HH 256
#define PED 63
#define TOPK 16
#define LINE 64
#define TS 32
#define NBX (BB/TS)   /* 512 */

/* workspace offsets (floats) — total ~5.07M floats ~= 19.4 MB */
#define OFF_KP   0u
#define OFF_VP   262144u
#define OFF_VPA  524288u
#define OFF_PE   786432u
#define OFF_PF   1818624u
#define OFF_EO   2867200u
#define OFF_RW   4964352u
#define OFF_CNT  4997120u
#define OFF_LIST 4997128u

__device__ __forceinline__ float wred_sum(float v) {
#pragma unroll
    for (int off = 32; off > 0; off >>= 1) v += __shfl_xor(v, off, 64);
    return v;
}

/* ------------ K1: kp = mem_k@wk, vp = mem_v@wv, vpa = vp@ad_w0[:64] ------------ */
__global__ __launch_bounds__(256) void k_proj(
    const float* __restrict__ mem_k, const float* __restrict__ mem_v,
    const float* __restrict__ wk, const float* __restrict__ wv,
    const float* __restrict__ aw0,
    float* __restrict__ kp, float* __restrict__ vp, float* __restrict__ vpa)
{
    int e = blockIdx.x >> 4;          /* E*16 blocks */
    int chunk = blockIdx.x & 15;
    __shared__ float swk[FF*FF], swv[FF*FF], sa0[FF*FF];
    __shared__ float svp[4][FF];
    for (int i = threadIdx.x; i < FF*FF; i += 256) {
        swk[i] = wk[e*FF*FF + i];
        swv[i] = wv[e*FF*FF + i];
        sa0[i] = aw0[(size_t)e*128*FF + i];   /* top 64 rows */
    }
    __syncthreads();
    int r4 = threadIdx.x >> 6;
    int f  = threadIdx.x & 63;
    for (int it = 0; it < 16; ++it) {
        int n = chunk*64 + it*4 + r4;
        const float* mk = mem_k + ((size_t)e*NN + n)*FF;
        const float* mv = mem_v + ((size_t)e*NN + n)*FF;
        float ak = 0.f, av = 0.f;
        for (int c = 0; c < FF; ++c) {
            ak = fmaf(mk[c], swk[c*FF+f], ak);
            av = fmaf(mv[c], swv[c*FF+f], av);
        }
        kp[((size_t)e*NN+n)*FF + f] = ak;
        vp[((size_t)e*NN+n)*FF + f] = av;
        svp[r4][f] = av;
        __syncthreads();
        float aa = 0.f;
        for (int c = 0; c < FF; ++c)
            aa = fmaf(svp[r4][c], sa0[c*FF+f], aa);
        vpa[((size_t)e*NN+n)*FF + f] = aa;
        __syncthreads();
    }
}

/* ------------ K2: routing + positional enc + param feats ------------ */
__global__ __launch_bounds__(256) void k_route(
    const float* __restrict__ x, const float* __restrict__ lines,
    const float* __restrict__ mg_w0, const float* __restrict__ mg_b0,
    const float* __restrict__ mg_w1, const float* __restrict__ mg_b1,
    float* __restrict__ pe_x, float* __restrict__ pfm,
    float* __restrict__ rawq, float* __restrict__ rw,
    int* __restrict__ counts, int* __restrict__ lists)
{
    __shared__ float slines[LINE*LINE];
    for (int i = threadIdx.x; i < LINE*LINE; i += 256) slines[i] = lines[i];
    __syncthreads();
    int b = blockIdx.x*256 + threadIdx.x;
    float4 xx = ((const float4*)x)[b];
    float c0 = xx.x, c1 = xx.y, c2 = xx.z, c3 = xx.w;

    /* param feats: lerp on lines */
    float p = c3 * (float)(LINE-1);
    float pfl = floorf(p);
    float w = p - pfl;
    int il = (int)pfl;
    int ih = (int)fminf(fmaxf(pfl + 1.f, 0.f), (float)(LINE-1));
    for (int c = 0; c < FF; ++c) {
        float lo = slines[c*LINE+il], hi = slines[c*LINE+ih];
        pfm[(size_t)b*FF + c] = lo + w*(hi-lo);
    }
    /* positional encoding: [c0,c1,c2, (sin,cos)x10 per coord] */
    float* pe = pe_x + (size_t)b*PED;
    pe[0]=c0; pe[1]=c1; pe[2]=c2;
    const float PI = 3.14159265358979323846f;
    float coords[3] = {c0,c1,c2};
#pragma unroll
    for (int cc = 0; cc < 3; ++cc) {
        float fr = PI;
        for (int k = 0; k < 10; ++k) {
            float s = coords[cc]*fr;
            pe[3 + cc*20 + k*2 + 0] = sinf(s);
            pe[3 + cc*20 + k*2 + 1] = cosf(s);
            fr *= 2.f;
        }
    }
    /* gating */
    float acc[4] = {mg_b1[0], mg_b1[1], mg_b1[2], mg_b1[3]};
    for (int j = 0; j < 64; ++j) {
        float h = fmaf(c0, mg_w0[j], fmaf(c1, mg_w0[64+j], fmaf(c2, mg_w0[128+j], mg_b0[j])));
        h = fmaxf(h, 0.f);
#pragma unroll
        for (int e4 = 0; e4 < 4; ++e4) acc[e4] = fmaf(h, mg_w1[j*4+e4], acc[e4]);
    }
#pragma unroll
    for (int e4 = 0; e4 < 4; ++e4) rawq[(size_t)b*4 + e4] = acc[e4];
    float m = fmaxf(fmaxf(acc[0],acc[1]), fmaxf(acc[2],acc[3]));
    float ex[4], den = 0.f;
#pragma unroll
    for (int e4 = 0; e4 < 4; ++e4) { ex[e4] = expf(acc[e4]-m); den += ex[e4]; }
    float pr[4];
#pragma unroll
    for (int e4 = 0; e4 < 4; ++e4) pr[e4] = fmaxf(ex[e4]/den, 1e-8f);
    int i0 = 0;
#pragma unroll
    for (int e4 = 1; e4 < 4; ++e4) if (pr[e4] > pr[i0]) i0 = e4;
    int i1 = -1;
#pragma unroll
    for (int e4 = 0; e4 < 4; ++e4) {
        if (e4 == i0) continue;
        if (i1 < 0 || pr[e4] > pr[i1]) i1 = e4;
    }
    float vs = pr[i0] + pr[i1];
    rw[b*2+0] = pr[i0]/vs;
    rw[b*2+1] = pr[i1]/vs;
    int p0 = atomicAdd(&counts[i0], 1);
    lists[i0*BB + p0] = b*2 + 0;
    int p1 = atomicAdd(&counts[i1], 1);
    lists[i1*BB + p1] = b*2 + 1;
}

/* ------------ K3: expert pipeline (bucketed) ------------ */
__global__ __launch_bounds__(256, 3) void k_expert(
    const float* __restrict__ pe_x, const float* __restrict__ pfm,
    const float* __restrict__ kp, const float* __restrict__ vp,
    const float* __restrict__ vpa,
    const float* __restrict__ enc_w0, const float* __restrict__ enc_b0,
    const float* __restrict__ enc_wh, const float* __restrict__ enc_bh,
    const float* __restrict__ enc_wo, const float* __restrict__ enc_bo,
    const float* __restrict__ ln_g, const float* __restrict__ ln_b,
    const float* __restrict__ wq,
    const float* __restrict__ aw0, const float* __restrict__ ab0,
    const float* __restrict__ aw1, const float* __restrict__ ab1,
    const float* __restrict__ adg, const float* __restrict__ adb,
    const int* __restrict__ counts, const int* __restrict__ lists,
    float* __restrict__ eo)
{
    const int e = blockIdx.y;
    const int base = blockIdx.x * TS;
    const int cnt = counts[e];
    if (base >= cnt) return;

    __shared__ float sh[TS*HH];     /* 32KB; later aliased as kp-chunk [64][68] and pl [4][64][16] */
    __shared__ float sq_[TS*FF];
    __shared__ float smlp[TS*FF];
    __shared__ float wr_l[4*TOPK];
    __shared__ int   tn_l[4*TOPK];
    __shared__ int   slist[TS];

    const int tid = threadIdx.x;
    const int lane = tid & 63;
    const int wv = tid >> 6;

    if (tid < TS) {
        int idx = base + tid;
        if (idx >= cnt) idx = cnt - 1;
        slist[tid] = lists[e*BB + idx];
    }
    __syncthreads();

    /* phase A: stage pe rows */
    for (int i = tid; i < TS*64; i += 256) {
        int s = i >> 6, j = i & 63;
        int bq = slist[s] >> 1;
        sh[s*HH + j] = (j < PED) ? pe_x[(size_t)bq*PED + j] : 0.f;
    }
    __syncthreads();

    float acc[8][4];

    /* L0: 63 -> 256, sin(30*(pe@W+b)) */
    {
        const float* W = enc_w0 + (size_t)e*PED*HH;
        const float* bia = enc_b0 + e*HH;
#pragma unroll
        for (int s = 0; s < 8; ++s) {
#pragma unroll
            for (int j = 0; j < 4; ++j) acc[s][j] = 0.f;
        }
#pragma unroll 1
        for (int k = 0; k < PED; ++k) {
            float w0_ = W[k*HH + lane];
            float w1_ = W[k*HH + lane + 64];
            float w2_ = W[k*HH + lane + 128];
            float w3_ = W[k*HH + lane + 192];
#pragma unroll
            for (int s = 0; s < 8; ++s) {
                float hv = sh[(wv*8+s)*HH + k];
                acc[s][0] = fmaf(hv, w0_, acc[s][0]);
                acc[s][1] = fmaf(hv, w1_, acc[s][1]);
                acc[s][2] = fmaf(hv, w2_, acc[s][2]);
                acc[s][3] = fmaf(hv, w3_, acc[s][3]);
            }
        }
#pragma unroll
        for (int j = 0; j < 4; ++j) {
            float bv = bia[lane + 64*j];
#pragma unroll
            for (int s = 0; s < 8; ++s)
                sh[(wv*8+s)*HH + lane + 64*j] = sinf(30.0f*(acc[s][j] + bv));
        }
    }

    /* L1, L2: 256 -> 256 */
#pragma unroll 1
    for (int layer = 0; layer < 2; ++layer) {
        const float* W = enc_wh + ((size_t)(e*2+layer))*HH*HH;
        const float* bia = enc_bh + (e*2+layer)*HH;
#pragma unroll
        for (int s = 0; s < 8; ++s) {
#pragma unroll
            for (int j = 0; j < 4; ++j) acc[s][j] = 0.f;
        }
#pragma unroll 1
        for (int k4 = 0; k4 < 64; ++k4) {
            float4 h4[8];
#pragma unroll
            for (int s = 0; s < 8; ++s)
                h4[s] = *(const float4*)&sh[(wv*8+s)*HH + k4*4];
#pragma unroll
            for (int kk = 0; kk < 4; ++kk) {
                float w0_ = W[(k4*4+kk)*HH + lane];
                float w1_ = W[(k4*4+kk)*HH + lane + 64];
                float w2_ = W[(k4*4+kk)*HH + lane + 128];
                float w3_ = W[(k4*4+kk)*HH + lane + 192];
#pragma unroll
                for (int s = 0; s < 8; ++s) {
                    float hv = (kk==0)?h4[s].x:((kk==1)?h4[s].y:((kk==2)?h4[s].z:h4[s].w));
                    acc[s][0] = fmaf(hv, w0_, acc[s][0]);
                    acc[s][1] = fmaf(hv, w1_, acc[s][1]);
                    acc[s][2] = fmaf(hv, w2_, acc[s][2]);
                    acc[s][3] = fmaf(hv, w3_, acc[s][3]);
                }
            }
        }
#pragma unroll
        for (int j = 0; j < 4; ++j) {
            float bv = bia[lane + 64*j];
#pragma unroll
            for (int s = 0; s < 8; ++s)
                sh[(wv*8+s)*HH + lane + 64*j] = sinf(30.0f*(acc[s][j] + bv));
        }
    }

    /* out layer: 256 -> 64 -> smlp */
    {
        const float* W = enc_wo + (size_t)e*HH*FF;
        const float* bia = enc_bo + e*FF;
        float a2o[8];
#pragma unroll
        for (int s = 0; s < 8; ++s) a2o[s] = 0.f;
#pragma unroll 1
        for (int k4 = 0; k4 < 64; ++k4) {
            float w0_ = W[(k4*4+0)*FF + lane];
            float w1_ = W[(k4*4+1)*FF + lane];
            float w2_ = W[(k4*4+2)*FF + lane];
            float w3_ = W[(k4*4+3)*FF + lane];
#pragma unroll
            for (int s = 0; s < 8; ++s) {
                float4 h4 = *(const float4*)&sh[(wv*8+s)*HH + k4*4];
                a2o[s] = fmaf(h4.x, w0_, a2o[s]);
                a2o[s] = fmaf(h4.y, w1_, a2o[s]);
                a2o[s] = fmaf(h4.z, w2_, a2o[s]);
                a2o[s] = fmaf(h4.w, w3_, a2o[s]);
            }
        }
        float bv = bia[lane];
#pragma unroll
        for (int s = 0; s < 8; ++s)
            smlp[(wv*8+s)*FF + lane] = a2o[s] + bv;
    }

    /* LN + q */
    {
        const float* Wq = wq + (size_t)e*FF*FF;
        float g = ln_g[lane], bb2 = ln_b[lane];
#pragma unroll 1
        for (int s8 = 0; s8 < 8; ++s8) {
            int s = wv*8 + s8;
            float hv = smlp[s*FF + lane];
            float mean = wred_sum(hv) * (1.f/64.f);
            float d = hv - mean;
            float var = wred_sum(d*d) * (1.f/64.f);
            float lnv = d * rsqrtf(var + 1e-5f) * g + bb2;
            sh[s*HH + lane] = lnv;
            float qa = 0.f;
#pragma unroll 1
            for (int c4 = 0; c4 < 16; ++c4) {
                float4 l4 = *(const float4*)&sh[s*HH + c4*4];
                qa = fmaf(l4.x, Wq[(c4*4+0)*FF + lane], qa);
                qa = fmaf(l4.y, Wq[(c4*4+1)*FF + lane], qa);
                qa = fmaf(l4.z, Wq[(c4*4+2)*FF + lane], qa);
                qa = fmaf(l4.w, Wq[(c4*4+3)*FF + lane], qa);
            }
            sq_[s*FF + lane] = qa;
        }
    }

    /* scores + top16 + adapter */
    float* skp = sh;                  /* [64][68] kp chunk */
    float* pl  = sh;                  /* [4][64][16] per-wave p/a2 buffer */
    const float* vpe  = vp  + (size_t)e*NN*FF;
    const float* vpae = vpa + (size_t)e*NN*FF;
    const float agv = adg[e*FF + lane], abv = adb[e*FF + lane];
    const float ab1v = ab1[e*FF + lane];
    const float* w1p = aw1 + (size_t)e*FF*FF;

#pragma unroll 1
    for (int pass = 0; pass < 2; ++pass) {
        float sc[4][16];
#pragma unroll
        for (int c = 0; c < 16; ++c) {
            __syncthreads();
            {
                int rt = tid >> 2;
                int cq = (tid & 3) * 16;
                const float* src = kp + ((size_t)e*NN + c*64 + rt)*FF + cq;
                float* dst = skp + rt*68 + cq;
                *(float4*)(dst+0)  = *(const float4*)(src+0);
                *(float4*)(dst+4)  = *(const float4*)(src+4);
                *(float4*)(dst+8)  = *(const float4*)(src+8);
                *(float4*)(dst+12) = *(const float4*)(src+12);
            }
            __syncthreads();
#pragma unroll
            for (int u = 0; u < 4; ++u) {
                int s = wv*8 + pass*4 + u;
                float a = 0.f;
#pragma unroll 1
                for (int f4 = 0; f4 < 16; ++f4) {
                    float4 q4 = *(const float4*)&sq_[s*FF + f4*4];
                    float4 k4 = *(const float4*)&skp[lane*68 + f4*4];
                    a = fmaf(q4.x, k4.x, a);
                    a = fmaf(q4.y, k4.y, a);
                    a = fmaf(q4.z, k4.z, a);
                    a = fmaf(q4.w, k4.w, a);
                }
                sc[u][c] = a;
            }
        }
        __syncthreads();   /* all waves done with skp before pl reuse */

#pragma unroll
        for (int u = 0; u < 4; ++u) {
            int s = wv*8 + pass*4 + u;
            int entry = slist[s];
            int bq = entry >> 1;
            /* pf contribution of adapter layer 1 (+ bias) */
            float pp = ab0[e*FF + lane];
            {
                const float* a0b = aw0 + ((size_t)e*128 + 64)*FF;
                const float* pfr = pfm + (size_t)bq*FF;
#pragma unroll 1
                for (int c4 = 0; c4 < 16; ++c4) {
                    float4 p4 = *(const float4*)&pfr[c4*4];
                    pp = fmaf(p4.x, a0b[(c4*4+0)*FF + lane], pp);
                    pp = fmaf(p4.y, a0b[(c4*4+1)*FF + lane], pp);
                    pp = fmaf(p4.z, a0b[(c4*4+2)*FF + lane], pp);
                    pp = fmaf(p4.w, a0b[(c4*4+3)*FF + lane], pp);
                }
            }
            /* 16 wave-argmax rounds; fused gather+relu of adapter layer-1 */
            unsigned taken = 0u;
            bool need = true;
            float bv = -1e30f; int bn = 0x7fffffff;
            float v0max = 0.f, wsum = 0.f;
#pragma unroll 1
            for (int r = 0; r < TOPK; ++r) {
                if (need) {
                    bv = -1e30f; bn = 0x7fffffff;
#pragma unroll
                    for (int c = 0; c < 16; ++c) {
                        float v = sc[u][c];
                        int n = c*64 + lane;
                        bool ok = !((taken >> c) & 1u);
                        bool better = ok && (v > bv || (v == bv && n < bn));
                        bv = better ? v : bv;
                        bn = better ? n : bn;
                    }
                    need = false;
                }
                float rv = bv; int rn = bn;
#pragma unroll
                for (int off = 32; off > 0; off >>= 1) {
                    float ov = __shfl_xor(rv, off, 64);
                    int on = __shfl_xor(rn, off, 64);
                    bool better = (ov > rv) || (ov == rv && on < rn);
                    rv = better ? ov : rv;
                    rn = better ? on : rn;
                }
                if (r == 0) v0max = rv;
                float wr = expf((rv - v0max) * 0.125f);
                wsum += wr;
                if (lane == 0) { wr_l[wv*TOPK + r] = wr; tn_l[wv*TOPK + r] = rn; }
                if ((rn & 63) == lane) { taken |= 1u << (rn >> 6); need = true; }
                float pre = vpae[(size_t)rn*FF + lane] + pp;
                pl[wv*1024 + lane*16 + r] = fmaxf(pre, 0.f);
            }
            /* adapter layer 2: a2[r] = sum_j p[j][r]*aw1[j][lane] */
            float a2[16];
#pragma unroll
            for (int r = 0; r < 16; ++r) a2[r] = ab1v;
#pragma unroll 1
            for (int j = 0; j < FF; ++j) {
                float w = w1p[j*FF + lane];
                const float* pj = &pl[wv*1024 + j*16];
                float4 p0 = *(const float4*)(pj+0);
                float4 p1 = *(const float4*)(pj+4);
                float4 p2 = *(const float4*)(pj+8);
                float4 p3 = *(const float4*)(pj+12);
                a2[0]=fmaf(p0.x,w,a2[0]);  a2[1]=fmaf(p0.y,w,a2[1]);
                a2[2]=fmaf(p0.z,w,a2[2]);  a2[3]=fmaf(p0.w,w,a2[3]);
                a2[4]=fmaf(p1.x,w,a2[4]);  a2[5]=fmaf(p1.y,w,a2[5]);
                a2[6]=fmaf(p1.z,w,a2[6]);  a2[7]=fmaf(p1.w,w,a2[7]);
                a2[8]=fmaf(p2.x,w,a2[8]);  a2[9]=fmaf(p2.y,w,a2[9]);
                a2[10]=fmaf(p2.z,w,a2[10]); a2[11]=fmaf(p2.w,w,a2[11]);
                a2[12]=fmaf(p3.x,w,a2[12]); a2[13]=fmaf(p3.y,w,a2[13]);
                a2[14]=fmaf(p3.z,w,a2[14]); a2[15]=fmaf(p3.w,w,a2[15]);
            }
#pragma unroll
            for (int r = 0; r < 16; ++r) pl[wv*1024 + lane*16 + r] = a2[r];
            /* LN + residual + attn-weighted sum */
            float outacc = 0.f;
#pragma unroll 1
            for (int r = 0; r < TOPK; ++r) {
                float av = pl[wv*1024 + lane*16 + r];
                float mean = wred_sum(av) * (1.f/64.f);
                float d = av - mean;
                float var = wred_sum(d*d) * (1.f/64.f);
                float lnv = d * rsqrtf(var + 1e-5f) * agv + abv;
                int n = tn_l[wv*TOPK + r];
                float vt = vpe[(size_t)n*FF + lane];
                outacc = fmaf(wr_l[wv*TOPK + r], vt + lnv, outacc);
            }
            float res = outacc / wsum + smlp[s*FF + lane];
            if (base + s < cnt) eo[(size_t)entry*FF + lane] = res;
        }
    }
}

/* ------------ K4: combine + final MLP ------------ */
__global__ __launch_bounds__(256, 3) void k_final(
    const float* __restrict__ eo, const float* __restrict__ rw,
    const float* __restrict__ fw0, const float* __restrict__ fb0,
    const float* __restrict__ fw1, const float* __restrict__ fb1,
    const float* __restrict__ fw2, const float* __restrict__ fb2,
    const float* __restrict__ fw3, const float* __restrict__ fb3,
    float* __restrict__ refined)
{
    __shared__ float sh[32*HH];
    const int tid = threadIdx.x, lane = tid & 63, wv = tid >> 6;
    const int sbase = blockIdx.x * 32;
    for (int i = tid; i < 32*64; i += 256) {
        int s = i >> 6, c = i & 63;
        int b = sbase + s;
        sh[s*HH + c] = rw[b*2]*eo[(size_t)(b*2)*FF + c]
                     + rw[b*2+1]*eo[(size_t)(b*2+1)*FF + c];
    }
    __syncthreads();
    float acc[8][4];
    /* L0: 64 -> 256 relu */
    {
#pragma unroll
        for (int s = 0; s < 8; ++s) {
#pragma unroll
            for (int j = 0; j < 4; ++j) acc[s][j] = 0.f;
        }
#pragma unroll 1
        for (int k4 = 0; k4 < 16; ++k4) {
#pragma unroll
            for (int kk = 0; kk < 4; ++kk) {
                float w0_ = fw0[(k4*4+kk)*HH + lane];
                float w1_ = fw0[(k4*4+kk)*HH + lane + 64];
                float w2_ = fw0[(k4*4+kk)*HH + lane + 128];
                float w3_ = fw0[(k4*4+kk)*HH + lane + 192];
#pragma unroll
                for (int s = 0; s < 8; ++s) {
                    float hv = sh[(wv*8+s)*HH + k4*4 + kk];
                    acc[s][0] = fmaf(hv, w0_, acc[s][0]);
                    acc[s][1] = fmaf(hv, w1_, acc[s][1]);
                    acc[s][2] = fmaf(hv, w2_, acc[s][2]);
                    acc[s][3] = fmaf(hv, w3_, acc[s][3]);
                }
            }
        }
#pragma unroll
        for (int j = 0; j < 4; ++j) {
            float bv = fb0[lane + 64*j];
#pragma unroll
            for (int s = 0; s < 8; ++s)
                sh[(wv*8+s)*HH + lane + 64*j] = fmaxf(acc[s][j] + bv, 0.f);
        }
    }
    /* L1, L2: 256 -> 256 relu */
#pragma unroll 1
    for (int layer = 0; layer < 2; ++layer) {
        const float* W  = layer ? fw2 : fw1;
        const float* bi = layer ? fb2 : fb1;
#pragma unroll
        for (int s = 0; s < 8; ++s) {
#pragma unroll
            for (int j = 0; j < 4; ++j) acc[s][j] = 0.f;
        }
#pragma unroll 1
        for (int k4 = 0; k4 < 64; ++k4) {
            float4 h4[8];
#pragma unroll
            for (int s = 0; s < 8; ++s)
                h4[s] = *(const float4*)&sh[(wv*8+s)*HH + k4*4];
#pragma unroll
            for (int kk = 0; kk < 4; ++kk) {
                float w0_ = W[(k4*4+kk)*HH + lane];
                float w1_ = W[(k4*4+kk)*HH + lane + 64];
                float w2_ = W[(k4*4+kk)*HH + lane + 128];
                float w3_ = W[(k4*4+kk)*HH + lane + 192];
#pragma unroll
                for (int s = 0; s < 8; ++s) {
                    float hv = (kk==0)?h4[s].x:((kk==1)?h4[s].y:((kk==2)?h4[s].z:h4[s].w));
                    acc[s][0] = fmaf(hv, w0_, acc[s][0]);
                    acc[s][1] = fmaf(hv, w1_, acc[s][1]);
                    acc[s][2] = fmaf(hv, w2_, acc[s][2]);
                    acc[s][3] = fmaf(hv, w3_, acc[s][3]);
                }
            }
        }
#pragma unroll
        for (int j = 0; j < 4; ++j) {
            float bv = bi[lane + 64*j];
#pragma unroll
            for (int s = 0; s < 8; ++s)
                sh[(wv*8+s)*HH + lane + 64*j] = fmaxf(acc[s][j] + bv, 0.f);
        }
    }
    /* L3: 256 -> 1, sigmoid */
#pragma unroll 1
    for (int s8 = 0; s8 < 8; ++s8) {
        int s = wv*8 + s8;
        float part = sh[s*HH + lane]*fw3[lane]
                   + sh[s*HH + lane+64]*fw3[lane+64]
                   + sh[s*HH + lane+128]*fw3[lane+128]
                   + sh[s*HH + lane+192]*fw3[lane+192];
        float tot = wred_sum(part) + fb3[0];
        float r = 1.f/(1.f + expf(-tot));
        if (lane == 0) refined[sbase + s] = r;
    }
}

extern "C" void kernel_launch(void* const* d_in, const int* in_sizes, int n_in,
                              void* d_out, int out_size, void* d_ws, size_t ws_size,
                              hipStream_t stream)
{
    const float* x      = (const float*)d_in[0];
    const float* lines  = (const float*)d_in[1];
    const float* mem_k  = (const float*)d_in[2];
    const float* mem_v  = (const float*)d_in[3];
    const float* enc_w0 = (const float*)d_in[4];
    const float* enc_b0 = (const float*)d_in[5];
    const float* enc_wh = (const float*)d_in[6];
    const float* enc_bh = (const float*)d_in[7];
    const float* enc_wo = (const float*)d_in[8];
    const float* enc_bo = (const float*)d_in[9];
    const float* ln_g   = (const float*)d_in[10];
    const float* ln_b   = (const float*)d_in[11];
    const float* wq     = (const float*)d_in[12];
    const float* wk     = (const float*)d_in[13];
    const float* wv_    = (const float*)d_in[14];
    const float* ad_w0  = (const float*)d_in[15];
    const float* ad_b0  = (const float*)d_in[16];
    const float* ad_w1  = (const float*)d_in[17];
    const float* ad_b1  = (const float*)d_in[18];
    const float* ad_g   = (const float*)d_in[19];
    const float* ad_b   = (const float*)d_in[20];
    const float* mg_w0  = (const float*)d_in[21];
    const float* mg_b0  = (const float*)d_in[22];
    const float* mg_w1  = (const float*)d_in[23];
    const float* mg_b1  = (const float*)d_in[24];
    const float* fw0    = (const float*)d_in[25];
    const float* fb0    = (const float*)d_in[26];
    const float* fw1    = (const float*)d_in[27];
    const float* fb1    = (const float*)d_in[28];
    const float* fw2    = (const float*)d_in[29];
    const float* fb2    = (const float*)d_in[30];
    const float* fw3    = (const float*)d_in[31];
    const float* fb3    = (const float*)d_in[32];

    float* out_ref = (float*)d_out;           /* refined: B */
    float* out_rq  = (float*)d_out + BB;      /* raw_q: B*4 */

    float* ws  = (float*)d_ws;
    float* kp  = ws + OFF_KP;
    float* vp  = ws + OFF_VP;
    float* vpa = ws + OFF_VPA;
    float* pe  = ws + OFF_PE;
    float* pfm = ws + OFF_PF;
    float* eo  = ws + OFF_EO;
    float* rw  = ws + OFF_RW;
    int*  cnts = (int*)(ws + OFF_CNT);
    int*  lst  = (int*)(ws + OFF_LIST);

    hipMemsetAsync(cnts, 0, EE*sizeof(int), stream);
    k_proj<<<dim3(EE*16), dim3(256), 0, stream>>>(mem_k, mem_v, wk, wv_, ad_w0, kp, vp, vpa);
    k_route<<<dim3(BB/256), dim3(256), 0, stream>>>(x, lines, mg_w0, mg_b0, mg_w1, mg_b1,
                                                    pe, pfm, out_rq, rw, cnts, lst);
    k_expert<<<dim3(NBX, EE), dim3(256), 0, stream>>>(pe, pfm, kp, vp, vpa,
        enc_w0, enc_b0, enc_wh, enc_bh, enc_wo, enc_bo, ln_g, ln_b, wq,
        ad_w0, ad_b0, ad_w1, ad_b1, ad_g, ad_b, cnts, lst, eo);
    k_final<<<dim3(BB/32), dim3(256), 0, stream>>>(eo, rw, fw0, fb0, fw1, fb1,
                                                   fw2, fb2, fw3, fb3, out_ref);
}